// Round 1
// baseline (322.984 us; speedup 1.0000x reference)
//
#include <hip/hip_runtime.h>
#include <stdint.h>
#include <stddef.h>

#define B_ 2
#define T_ 2048
#define D_ 1024
#define H_ 16
#define U_ 64
#define M_ (B_ * T_)   // 4096
#define N_ (H_ * U_)   // 1024

typedef __attribute__((ext_vector_type(4))) float f32x4;
typedef __attribute__((ext_vector_type(8))) short s16x8;
typedef __attribute__((ext_vector_type(8))) __bf16 b16x8;

static_assert(sizeof(s16x8) == 16, "frag size");

__device__ __forceinline__ unsigned short f2bf(float f) {
  unsigned int u = __float_as_uint(f);
  u += 0x7FFFu + ((u >> 16) & 1u);     // RNE
  return (unsigned short)(u >> 16);
}

// --- MFMA wrapper: SFINAE hedge — works whether the builtin takes short8 or bf16x8
template <typename V>
__device__ __forceinline__ auto mfma16_impl(V a, V b, f32x4 c, int)
    -> decltype(__builtin_amdgcn_mfma_f32_16x16x32_bf16(a, b, c, 0, 0, 0)) {
  return __builtin_amdgcn_mfma_f32_16x16x32_bf16(a, b, c, 0, 0, 0);
}
template <typename V>
__device__ __forceinline__ f32x4 mfma16_impl(V a, V b, f32x4 c, long) {
  return __builtin_amdgcn_mfma_f32_16x16x32_bf16(
      __builtin_bit_cast(b16x8, a), __builtin_bit_cast(b16x8, b), c, 0, 0, 0);
}
__device__ __forceinline__ f32x4 mfma16(s16x8 a, s16x8 b, f32x4 c) {
  return mfma16_impl(a, b, c, 0);
}

// ---------------------------------------------------------------- K0: W -> W^T (bf16)
__global__ void wtrans_kernel(const float* __restrict__ w0, const float* __restrict__ w1,
                              const float* __restrict__ w2, const float* __restrict__ w3,
                              unsigned short* __restrict__ o0, unsigned short* __restrict__ o1,
                              unsigned short* __restrict__ o2, unsigned short* __restrict__ o3) {
  __shared__ float tile[64][65];
  const float* w;
  unsigned short* o;
  switch (blockIdx.z) {
    case 0: w = w0; o = o0; break;
    case 1: w = w1; o = o1; break;
    case 2: w = w2; o = o2; break;
    default: w = w3; o = o3; break;
  }
  const int kb = blockIdx.y * 64, nb = blockIdx.x * 64;
  const int tid = threadIdx.x;
  const int r0 = tid >> 6, c = tid & 63;
#pragma unroll
  for (int i = 0; i < 16; i++) {
    int r = i * 4 + r0;
    tile[r][c] = w[(size_t)(kb + r) * 1024 + nb + c];
  }
  __syncthreads();
#pragma unroll
  for (int i = 0; i < 16; i++) {
    int r = i * 4 + r0;   // row of the transposed output (n index)
    o[(size_t)(nb + r) * 1024 + kb + c] = f2bf(tile[c][r]);
  }
}

// ---------------------------------------------------------------- K1: xb = bf16(x * mask)
__global__ void xmask_kernel(const float* __restrict__ x, const int* __restrict__ mask,
                             unsigned short* __restrict__ xb) {
  const int idx = (blockIdx.x * 256 + threadIdx.x) * 4;  // 4 elems/thread
  const int row = idx >> 10;                             // b*T + t
  const float m = (float)mask[row];
  float4 v = *(const float4*)(x + idx);
  ushort4 o;
  o.x = f2bf(v.x * m);
  o.y = f2bf(v.y * m);
  o.z = f2bf(v.z * m);
  o.w = f2bf(v.w * m);
  *(ushort4*)(xb + idx) = o;
}

// ---------------------------------------------------------------- GEMM body (NT):
// C[m][n] = sum_k A[m][k] * Bt[n][k],  M=4096, N=1024, K=1024. 128x128 tile, 4 waves.
template <bool OUTF32>
__device__ __forceinline__ void gemm_body(const unsigned short* __restrict__ A,
                                          const unsigned short* __restrict__ Bt,
                                          void* __restrict__ Cout) {
  constexpr int Kd = 1024, Nd = 1024;
  constexpr int LDP = 40;  // padded LDS row (shorts): 80B stride, 16B aligned, spreads banks
  __shared__ unsigned short la[128 * LDP];
  __shared__ unsigned short lb[128 * LDP];
  const int tid = threadIdx.x;
  const int lane = tid & 63;
  const int mb = blockIdx.y * 128, nb = blockIdx.x * 128;
  const int w = tid >> 6;
  const int wm = (w >> 1) * 64, wn = (w & 1) * 64;
  const int srow = tid >> 2;          // 0..63
  const int scol = (tid & 3) * 8;     // 0,8,16,24
  const int lr = lane & 15, lg = lane >> 4;

  const unsigned short* ga = A + (size_t)(mb + srow) * Kd + scol;
  const unsigned short* gb = Bt + (size_t)(nb + srow) * Kd + scol;
  s16x8 ra0 = *(const s16x8*)ga;
  s16x8 ra1 = *(const s16x8*)(ga + (size_t)64 * Kd);
  s16x8 rb0 = *(const s16x8*)gb;
  s16x8 rb1 = *(const s16x8*)(gb + (size_t)64 * Kd);

  f32x4 acc[4][4] = {};

  for (int kt = 0; kt < Kd; kt += 32) {
    __syncthreads();  // previous frag reads done
    *(s16x8*)(la + srow * LDP + scol) = ra0;
    *(s16x8*)(la + (srow + 64) * LDP + scol) = ra1;
    *(s16x8*)(lb + srow * LDP + scol) = rb0;
    *(s16x8*)(lb + (srow + 64) * LDP + scol) = rb1;
    __syncthreads();  // stores visible
    if (kt + 32 < Kd) {  // prefetch next K-step under the MFMAs
      ga += 32; gb += 32;
      ra0 = *(const s16x8*)ga;
      ra1 = *(const s16x8*)(ga + (size_t)64 * Kd);
      rb0 = *(const s16x8*)gb;
      rb1 = *(const s16x8*)(gb + (size_t)64 * Kd);
    }
    s16x8 af[4], bfr[4];
#pragma unroll
    for (int i = 0; i < 4; i++)
      af[i] = *(const s16x8*)(la + (wm + i * 16 + lr) * LDP + lg * 8);
#pragma unroll
    for (int j = 0; j < 4; j++)
      bfr[j] = *(const s16x8*)(lb + (wn + j * 16 + lr) * LDP + lg * 8);
#pragma unroll
    for (int i = 0; i < 4; i++)
#pragma unroll
      for (int j = 0; j < 4; j++)
        acc[i][j] = mfma16(af[i], bfr[j], acc[i][j]);
  }

  // epilogue: lane holds C[row=(lg*4+r)][col=lr] per 16x16 frag
#pragma unroll
  for (int i = 0; i < 4; i++)
#pragma unroll
    for (int j = 0; j < 4; j++) {
      const int col = nb + wn + j * 16 + lr;
      const int rowb = mb + wm + i * 16 + lg * 4;
      if (OUTF32) {
        float* C = (float*)Cout;
#pragma unroll
        for (int r = 0; r < 4; r++) C[(size_t)(rowb + r) * Nd + col] = acc[i][j][r];
      } else {
        unsigned short* C = (unsigned short*)Cout;
#pragma unroll
        for (int r = 0; r < 4; r++) C[(size_t)(rowb + r) * Nd + col] = f2bf(acc[i][j][r]);
      }
    }
}

// K2: QKV projections (z selects weight/output), bf16 out [M, 1024]
__global__ __launch_bounds__(256) void gemm_qkv(const unsigned short* __restrict__ A,
                                                const unsigned short* __restrict__ wq,
                                                const unsigned short* __restrict__ wk,
                                                const unsigned short* __restrict__ wv,
                                                unsigned short* __restrict__ cq,
                                                unsigned short* __restrict__ ck,
                                                unsigned short* __restrict__ cv) {
  const unsigned short* Bt;
  unsigned short* C;
  if (blockIdx.z == 0) { Bt = wq; C = cq; }
  else if (blockIdx.z == 1) { Bt = wk; C = ck; }
  else { Bt = wv; C = cv; }
  gemm_body<false>(A, Bt, C);
}

// K4: output projection, fp32 out
__global__ __launch_bounds__(256) void gemm_out(const unsigned short* __restrict__ A,
                                                const unsigned short* __restrict__ woT,
                                                float* __restrict__ C) {
  gemm_body<true>(A, woT, C);
}

// ---------------------------------------------------------------- K2.5: V -> V^T per (b,h)
// vb [b*T+t][h*64+u] -> vt [(bh*64+u)][t]
__global__ void vtrans_kernel(const unsigned short* __restrict__ vb,
                              unsigned short* __restrict__ vt) {
  __shared__ unsigned short tile[64][65];
  const int bh = blockIdx.y;           // 0..31
  const int tb = blockIdx.x * 64;      // t base
  const int tid = threadIdx.x;
  const int r0 = tid >> 6, c = tid & 63;
  const unsigned short* src = vb + ((size_t)(bh >> 4) * T_ + tb) * 1024 + (bh & 15) * 64;
#pragma unroll
  for (int i = 0; i < 16; i++) {
    int r = i * 4 + r0;
    tile[r][c] = src[(size_t)r * 1024 + c];
  }
  __syncthreads();
  unsigned short* dst = vt + (size_t)bh * 64 * T_ + tb;
#pragma unroll
  for (int i = 0; i < 16; i++) {
    int u = i * 4 + r0;
    dst[(size_t)u * T_ + c] = tile[c][u];
  }
}

// ---------------------------------------------------------------- K3: flash attention
// Q,K: [M][1024] bf16 (row = b*T+t, col = h*64+u); Vt: [B*H][64][T] bf16
// out att: [M][1024] bf16. 4 waves/block, 16 q-rows/wave, KVBLK=32, causal + pad-mask.
__global__ __launch_bounds__(256) void attn_kernel(const unsigned short* __restrict__ Q,
                                                   const unsigned short* __restrict__ K,
                                                   const unsigned short* __restrict__ Vt,
                                                   const int* __restrict__ mask,
                                                   unsigned short* __restrict__ att) {
  __shared__ unsigned short pbuf[4][16][40];  // per-wave P repack, 80B row stride
  const int tid = threadIdx.x;
  const int w = tid >> 6, lane = tid & 63;
  const int bh = blockIdx.y;
  const int b = bh >> 4, h = bh & 15;
  const int qbase = blockIdx.x * 64 + w * 16;
  const int li = lane & 15, lg = lane >> 4;
  const int iglob = qbase + li;

  // Q fragments (B-operand of swapped QK^T): 8 contiguous u per lane, 2 halves of U=64
  const unsigned short* qrow = Q + ((size_t)(b * T_) + iglob) * 1024 + h * 64;
  s16x8 qf0 = *(const s16x8*)(qrow + lg * 8);
  s16x8 qf1 = *(const s16x8*)(qrow + 32 + lg * 8);

  const unsigned short* Kbase = K + (size_t)(b * T_) * 1024 + h * 64;
  const unsigned short* Vtb = Vt + (size_t)bh * 64 * T_;
  const int* mk = mask + b * T_;

  float mrun = -1e30f, lrun = 0.f;
  f32x4 acc[4] = {};
  const float CS = 0.125f * 1.44269504089f;       // 1/sqrt(U) * log2(e)
  const float PB = 10000.0f * 1.44269504089f;     // pad bias in log2 domain

  const int ntiles = (qbase + 16 + 31) >> 5;
  for (int jt = 0; jt < ntiles; jt++) {
    const int jbase = jt * 32;
    // ---- QK^T (swapped: mfma(K, Q) -> S^T: lane holds j=lg*4+r (+16), i=li)
    f32x4 s0 = {}, s1 = {};
    {
      const unsigned short* kr0 = Kbase + (size_t)(jbase + li) * 1024;
      const unsigned short* kr1 = Kbase + (size_t)(jbase + 16 + li) * 1024;
      s16x8 ka = *(const s16x8*)(kr0 + lg * 8);
      s16x8 kb = *(const s16x8*)(kr0 + 32 + lg * 8);
      s0 = mfma16(ka, qf0, s0);
      s0 = mfma16(kb, qf1, s0);
      s16x8 kc = *(const s16x8*)(kr1 + lg * 8);
      s16x8 kd = *(const s16x8*)(kr1 + 32 + lg * 8);
      s1 = mfma16(kc, qf0, s1);
      s1 = mfma16(kd, qf1, s1);
    }
    // ---- online softmax (log2 domain)
    float zv[8];
    float pmax = -1e30f;
#pragma unroll
    for (int hf = 0; hf < 2; hf++)
#pragma unroll
      for (int r = 0; r < 4; r++) {
        const int jg = jbase + hf * 16 + lg * 4 + r;
        float z = (hf ? s1[r] : s0[r]) * CS;
        z -= (1.0f - (float)mk[jg]) * PB;       // key padding bias
        if (jg > iglob) z = -1e30f;             // causal
        zv[hf * 4 + r] = z;
        pmax = fmaxf(pmax, z);
      }
    pmax = fmaxf(pmax, __shfl_xor(pmax, 16));
    pmax = fmaxf(pmax, __shfl_xor(pmax, 32));
    const float mnew = fmaxf(mrun, pmax);
    const float alpha = exp2f(mrun - mnew);
    float psum = 0.f;
    unsigned short pb16[8];
#pragma unroll
    for (int e = 0; e < 8; e++) {
      float p = exp2f(zv[e] - mnew);
      psum += p;
      pb16[e] = f2bf(p);
    }
    psum += __shfl_xor(psum, 16);
    psum += __shfl_xor(psum, 32);
    lrun = lrun * alpha + psum;
    mrun = mnew;
#pragma unroll
    for (int ut = 0; ut < 4; ut++) acc[ut] *= alpha;

    // ---- repack P through LDS: pbuf[i][jloc] = P[i][jbase+jloc]
#pragma unroll
    for (int hf = 0; hf < 2; hf++) {
      ushort4 pk;
      pk.x = pb16[hf * 4 + 0];
      pk.y = pb16[hf * 4 + 1];
      pk.z = pb16[hf * 4 + 2];
      pk.w = pb16[hf * 4 + 3];
      *(ushort4*)(&pbuf[w][li][hf * 16 + lg * 4]) = pk;
    }
    // same-wave write->read: compiler inserts lgkmcnt wait (no barrier needed)
    s16x8 pfrag = *(const s16x8*)(&pbuf[w][li][lg * 8]);

    // ---- PV: O^T[u][i] += V^T[u][j] P^T[j][i]
#pragma unroll
    for (int ut = 0; ut < 4; ut++) {
      s16x8 vf = *(const s16x8*)(Vtb + (size_t)(ut * 16 + li) * T_ + jbase + lg * 8);
      acc[ut] = mfma16(vf, pfrag, acc[ut]);
    }
  }

  const float inv = 1.0f / lrun;
  unsigned short* arow = att + ((size_t)(b * T_) + iglob) * 1024 + h * 64;
#pragma unroll
  for (int ut = 0; ut < 4; ut++) {
    ushort4 o;
    o.x = f2bf(acc[ut][0] * inv);
    o.y = f2bf(acc[ut][1] * inv);
    o.z = f2bf(acc[ut][2] * inv);
    o.w = f2bf(acc[ut][3] * inv);
    *(ushort4*)(arow + ut * 16 + lg * 4) = o;
  }
}

// ----------------------------------------------------------------
extern "C" void kernel_launch(void* const* d_in, const int* in_sizes, int n_in,
                              void* d_out, int out_size, void* d_ws, size_t ws_size,
                              hipStream_t stream) {
  const float* x = (const float*)d_in[0];
  const int* mask = (const int*)d_in[1];
  const float* Wq = (const float*)d_in[2];
  const float* Wk = (const float*)d_in[3];
  const float* Wv = (const float*)d_in[4];
  const float* Wo = (const float*)d_in[5];

  const size_t MB = 1u << 20;
  char* ws = (char*)d_ws;
  unsigned short* wqT = (unsigned short*)(ws + 0 * MB);
  unsigned short* wkT = (unsigned short*)(ws + 2 * MB);
  unsigned short* wvT = (unsigned short*)(ws + 4 * MB);
  unsigned short* woT = (unsigned short*)(ws + 6 * MB);
  unsigned short* xb  = (unsigned short*)(ws + 8 * MB);   // 8MB; dead after QKV GEMM
  unsigned short* qb  = (unsigned short*)(ws + 16 * MB);  // 8MB
  unsigned short* kb  = (unsigned short*)(ws + 24 * MB);  // 8MB
  unsigned short* vb  = (unsigned short*)(ws + 32 * MB);  // 8MB; dead after vtrans
  unsigned short* vt  = xb;                               // reuse xb slot
  unsigned short* att = vb;                               // reuse vb slot
  (void)ws_size; (void)in_sizes; (void)n_in; (void)out_size;

  wtrans_kernel<<<dim3(16, 16, 4), 256, 0, stream>>>(Wq, Wk, Wv, Wo, wqT, wkT, wvT, woT);
  xmask_kernel<<<dim3(4096), 256, 0, stream>>>(x, mask, xb);
  gemm_qkv<<<dim3(8, 32, 3), 256, 0, stream>>>(xb, wqT, wkT, wvT, qb, kb, vb);
  vtrans_kernel<<<dim3(32, 32), 256, 0, stream>>>(vb, vt);
  attn_kernel<<<dim3(32, 32), 256, 0, stream>>>(qb, kb, vt, mask, att);
  gemm_out<<<dim3(8, 32), 256, 0, stream>>>(att, woT, (float*)d_out);
}

// Round 2
// 181.853 us; speedup vs baseline: 1.7761x; 1.7761x over previous
//
#include <hip/hip_runtime.h>
#include <stdint.h>
#include <stddef.h>

#define B_ 2
#define T_ 2048
#define D_ 1024
#define H_ 16
#define U_ 64
#define M_ (B_ * T_)   // 4096
#define N_ (H_ * U_)   // 1024

typedef __attribute__((ext_vector_type(4))) float f32x4;
typedef __attribute__((ext_vector_type(8))) short s16x8;
typedef __attribute__((ext_vector_type(8))) __bf16 b16x8;

static_assert(sizeof(s16x8) == 16, "frag size");

__device__ __forceinline__ unsigned short f2bf(float f) {
  unsigned int u = __float_as_uint(f);
  u += 0x7FFFu + ((u >> 16) & 1u);     // RNE
  return (unsigned short)(u >> 16);
}

// --- MFMA wrapper: SFINAE hedge — works whether the builtin takes short8 or bf16x8
template <typename V>
__device__ __forceinline__ auto mfma16_impl(V a, V b, f32x4 c, int)
    -> decltype(__builtin_amdgcn_mfma_f32_16x16x32_bf16(a, b, c, 0, 0, 0)) {
  return __builtin_amdgcn_mfma_f32_16x16x32_bf16(a, b, c, 0, 0, 0);
}
template <typename V>
__device__ __forceinline__ f32x4 mfma16_impl(V a, V b, f32x4 c, long) {
  return __builtin_amdgcn_mfma_f32_16x16x32_bf16(
      __builtin_bit_cast(b16x8, a), __builtin_bit_cast(b16x8, b), c, 0, 0, 0);
}
__device__ __forceinline__ f32x4 mfma16(s16x8 a, s16x8 b, f32x4 c) {
  return mfma16_impl(a, b, c, 0);
}

// ---------------------------------------------------------------- K0: W -> W^T (bf16)
__global__ void wtrans_kernel(const float* __restrict__ w0, const float* __restrict__ w1,
                              const float* __restrict__ w2, const float* __restrict__ w3,
                              unsigned short* __restrict__ o0, unsigned short* __restrict__ o1,
                              unsigned short* __restrict__ o2, unsigned short* __restrict__ o3) {
  __shared__ float tile[64][65];
  const float* w;
  unsigned short* o;
  switch (blockIdx.z) {
    case 0: w = w0; o = o0; break;
    case 1: w = w1; o = o1; break;
    case 2: w = w2; o = o2; break;
    default: w = w3; o = o3; break;
  }
  const int kb = blockIdx.y * 64, nb = blockIdx.x * 64;
  const int tid = threadIdx.x;
  const int r0 = tid >> 6, c = tid & 63;
#pragma unroll
  for (int i = 0; i < 16; i++) {
    int r = i * 4 + r0;
    tile[r][c] = w[(size_t)(kb + r) * 1024 + nb + c];
  }
  __syncthreads();
#pragma unroll
  for (int i = 0; i < 16; i++) {
    int r = i * 4 + r0;   // row of the transposed output (n index)
    o[(size_t)(nb + r) * 1024 + kb + c] = f2bf(tile[c][r]);
  }
}

// ---------------------------------------------------------------- K1: xb = bf16(x * mask)
__global__ void xmask_kernel(const float* __restrict__ x, const int* __restrict__ mask,
                             unsigned short* __restrict__ xb) {
  const int idx = (blockIdx.x * 256 + threadIdx.x) * 4;  // 4 elems/thread
  const int row = idx >> 10;                             // b*T + t
  const float m = (float)mask[row];
  float4 v = *(const float4*)(x + idx);
  ushort4 o;
  o.x = f2bf(v.x * m);
  o.y = f2bf(v.y * m);
  o.z = f2bf(v.z * m);
  o.w = f2bf(v.w * m);
  *(ushort4*)(xb + idx) = o;
}

// ---------------------------------------------------------------- GEMM body (NT):
// C[m][n] = sum_k A[m][k] * Bt[n][k],  M=4096, N=1024, K=1024. 128x128 tile, 4 waves.
template <bool OUTF32>
__device__ __forceinline__ void gemm_body(const unsigned short* __restrict__ A,
                                          const unsigned short* __restrict__ Bt,
                                          void* __restrict__ Cout) {
  constexpr int Kd = 1024, Nd = 1024;
  constexpr int LDP = 40;  // padded LDS row (shorts): 80B stride, 16B aligned, spreads banks
  __shared__ unsigned short la[128 * LDP];
  __shared__ unsigned short lb[128 * LDP];
  const int tid = threadIdx.x;
  const int lane = tid & 63;
  const int mb = blockIdx.y * 128, nb = blockIdx.x * 128;
  const int w = tid >> 6;
  const int wm = (w >> 1) * 64, wn = (w & 1) * 64;
  const int srow = tid >> 2;          // 0..63
  const int scol = (tid & 3) * 8;     // 0,8,16,24
  const int lr = lane & 15, lg = lane >> 4;

  const unsigned short* ga = A + (size_t)(mb + srow) * Kd + scol;
  const unsigned short* gb = Bt + (size_t)(nb + srow) * Kd + scol;
  s16x8 ra0 = *(const s16x8*)ga;
  s16x8 ra1 = *(const s16x8*)(ga + (size_t)64 * Kd);
  s16x8 rb0 = *(const s16x8*)gb;
  s16x8 rb1 = *(const s16x8*)(gb + (size_t)64 * Kd);

  f32x4 acc[4][4] = {};

  for (int kt = 0; kt < Kd; kt += 32) {
    __syncthreads();  // previous frag reads done
    *(s16x8*)(la + srow * LDP + scol) = ra0;
    *(s16x8*)(la + (srow + 64) * LDP + scol) = ra1;
    *(s16x8*)(lb + srow * LDP + scol) = rb0;
    *(s16x8*)(lb + (srow + 64) * LDP + scol) = rb1;
    __syncthreads();  // stores visible
    if (kt + 32 < Kd) {  // prefetch next K-step under the MFMAs
      ga += 32; gb += 32;
      ra0 = *(const s16x8*)ga;
      ra1 = *(const s16x8*)(ga + (size_t)64 * Kd);
      rb0 = *(const s16x8*)gb;
      rb1 = *(const s16x8*)(gb + (size_t)64 * Kd);
    }
    s16x8 af[4], bfr[4];
#pragma unroll
    for (int i = 0; i < 4; i++)
      af[i] = *(const s16x8*)(la + (wm + i * 16 + lr) * LDP + lg * 8);
#pragma unroll
    for (int j = 0; j < 4; j++)
      bfr[j] = *(const s16x8*)(lb + (wn + j * 16 + lr) * LDP + lg * 8);
#pragma unroll
    for (int i = 0; i < 4; i++)
#pragma unroll
      for (int j = 0; j < 4; j++)
        acc[i][j] = mfma16(af[i], bfr[j], acc[i][j]);
  }

  // epilogue: lane holds C[row=(lg*4+r)][col=lr] per 16x16 frag
#pragma unroll
  for (int i = 0; i < 4; i++)
#pragma unroll
    for (int j = 0; j < 4; j++) {
      const int col = nb + wn + j * 16 + lr;
      const int rowb = mb + wm + i * 16 + lg * 4;
      if (OUTF32) {
        float* C = (float*)Cout;
#pragma unroll
        for (int r = 0; r < 4; r++) C[(size_t)(rowb + r) * Nd + col] = acc[i][j][r];
      } else {
        unsigned short* C = (unsigned short*)Cout;
#pragma unroll
        for (int r = 0; r < 4; r++) C[(size_t)(rowb + r) * Nd + col] = f2bf(acc[i][j][r]);
      }
    }
}

// K2: QKV projections (z selects weight/output), bf16 out [M, 1024]
__global__ __launch_bounds__(256) void gemm_qkv(const unsigned short* __restrict__ A,
                                                const unsigned short* __restrict__ wq,
                                                const unsigned short* __restrict__ wk,
                                                const unsigned short* __restrict__ wv,
                                                unsigned short* __restrict__ cq,
                                                unsigned short* __restrict__ ck,
                                                unsigned short* __restrict__ cv) {
  const unsigned short* Bt;
  unsigned short* C;
  if (blockIdx.z == 0) { Bt = wq; C = cq; }
  else if (blockIdx.z == 1) { Bt = wk; C = ck; }
  else { Bt = wv; C = cv; }
  gemm_body<false>(A, Bt, C);
}

// K4: output projection, fp32 out
__global__ __launch_bounds__(256) void gemm_out(const unsigned short* __restrict__ A,
                                                const unsigned short* __restrict__ woT,
                                                float* __restrict__ C) {
  gemm_body<true>(A, woT, C);
}

// ---------------------------------------------------------------- K2.5: V -> V^T per (b,h)
// vb [b*T+t][h*64+u] -> vt [(bh*64+u)][t]
__global__ void vtrans_kernel(const unsigned short* __restrict__ vb,
                              unsigned short* __restrict__ vt) {
  __shared__ unsigned short tile[64][65];
  const int bh = blockIdx.y;           // 0..31
  const int tb = blockIdx.x * 64;      // t base
  const int tid = threadIdx.x;
  const int r0 = tid >> 6, c = tid & 63;
  const unsigned short* src = vb + ((size_t)(bh >> 4) * T_ + tb) * 1024 + (bh & 15) * 64;
#pragma unroll
  for (int i = 0; i < 16; i++) {
    int r = i * 4 + r0;
    tile[r][c] = src[(size_t)r * 1024 + c];
  }
  __syncthreads();
  unsigned short* dst = vt + (size_t)bh * 64 * T_ + tb;
#pragma unroll
  for (int i = 0; i < 16; i++) {
    int u = i * 4 + r0;
    dst[(size_t)u * T_ + c] = tile[c][u];
  }
}

// ---------------------------------------------------------------- K3: flash attention v2
// One wave (64 threads) per 32 q-rows of one (b,h). KVBLK=64.
// Q,K: [M][1024] bf16 (row = b*T+t, col = h*64+u); Vt: [B*H][64][T] bf16
// out att: [M][1024] bf16.
// grid: (32 bh, 64 qgroups), qg = 63 - blockIdx.y (longest blocks dispatch first).
__global__ __launch_bounds__(64, 3) void attn2_kernel(const unsigned short* __restrict__ Q,
                                                      const unsigned short* __restrict__ K,
                                                      const unsigned short* __restrict__ Vt,
                                                      const int* __restrict__ mask,
                                                      unsigned short* __restrict__ att) {
  __shared__ unsigned short pbuf[32 * 64];  // P repack, XOR-swizzled, 8KB
  const int lane = threadIdx.x & 63;
  const int li = lane & 15, lg = lane >> 4;
  const int bh = blockIdx.x;
  const int b = bh >> 4, h = bh & 15;
  const int qg = 63 - blockIdx.y;
  const int q0 = qg * 32;

  const float CS = 0.125f * 1.44269504089f;   // 1/sqrt(U) * log2(e)
  const float PB = 10000.0f * 1.44269504089f; // pad bias, log2 domain

  // Q fragments (B-operand of swapped QK^T): qf[ifrag][kslice]
  s16x8 qf[2][2];
#pragma unroll
  for (int f = 0; f < 2; f++) {
    const unsigned short* qrow = Q + ((size_t)(b * T_) + q0 + f * 16 + li) * 1024 + h * 64;
    qf[f][0] = *(const s16x8*)(qrow + lg * 8);
    qf[f][1] = *(const s16x8*)(qrow + 32 + lg * 8);
  }

  const unsigned short* Kb = K + (size_t)(b * T_) * 1024 + h * 64;
  const unsigned short* Vtb = Vt + (size_t)bh * 64 * T_;
  const int* mk = mask + b * T_;

  // lane's i per ifrag (for causal compare)
  const int iq0 = q0 + li, iq1 = q0 + 16 + li;

  float mrun[2] = {-1e30f, -1e30f}, lrun[2] = {0.f, 0.f};
  f32x4 acc[4][2] = {};  // [ufrag][ifrag]

  // XOR-swizzled pbuf byte offsets (loop-invariant)
  const int xr = (li & 3) << 5;
  char* pbb = (char*)pbuf;

  const int ntiles = (q0 + 95) >> 6;  // ceil((q0+32)/64)
  for (int t = 0; t < ntiles; t++) {
    const int jb = t * 64;
    const bool diag = (jb + 64 > q0);  // wave-uniform

    // ---- QK^T (swapped): s[jf][if], lane holds j = jb+jf*16+lg*4+r, i = q0+if*16+li
    f32x4 s[4][2] = {};
#pragma unroll
    for (int jf = 0; jf < 4; jf++) {
      const unsigned short* kr = Kb + (size_t)(jb + jf * 16 + li) * 1024;
      s16x8 ka = *(const s16x8*)(kr + lg * 8);
      s16x8 kc = *(const s16x8*)(kr + 32 + lg * 8);
      s[jf][0] = mfma16(ka, qf[0][0], s[jf][0]);
      s[jf][0] = mfma16(kc, qf[0][1], s[jf][0]);
      s[jf][1] = mfma16(ka, qf[1][0], s[jf][1]);
      s[jf][1] = mfma16(kc, qf[1][1], s[jf][1]);
    }

    // ---- key padding bias, hoisted per tile (shared across ifrags)
    float bias[4][4];
#pragma unroll
    for (int jf = 0; jf < 4; jf++) {
      int4 mv = *(const int4*)(mk + jb + jf * 16 + lg * 4);
      bias[jf][0] = mv.x ? 0.f : -PB;
      bias[jf][1] = mv.y ? 0.f : -PB;
      bias[jf][2] = mv.z ? 0.f : -PB;
      bias[jf][3] = mv.w ? 0.f : -PB;
    }

    // ---- online softmax per ifrag (log2 domain)
#pragma unroll
    for (int f = 0; f < 2; f++) {
      const int iq = f ? iq1 : iq0;
      float z[16];
      float pmax = -1e30f;
#pragma unroll
      for (int jf = 0; jf < 4; jf++)
#pragma unroll
        for (int r = 0; r < 4; r++) {
          float zz = fmaf(s[jf][f][r], CS, bias[jf][r]);
          if (diag) {
            const int j = jb + jf * 16 + lg * 4 + r;
            if (j > iq) zz = -1e30f;
          }
          z[jf * 4 + r] = zz;
          pmax = fmaxf(pmax, zz);
        }
      pmax = fmaxf(pmax, __shfl_xor(pmax, 16));
      pmax = fmaxf(pmax, __shfl_xor(pmax, 32));
      float mnew = mrun[f];
      if (!__all(pmax <= mrun[f])) {  // exact-skip rescale (alpha==1 when skipped)
        mnew = fmaxf(mrun[f], pmax);
        const float alpha = exp2f(mrun[f] - mnew);
        lrun[f] *= alpha;
#pragma unroll
        for (int uf = 0; uf < 4; uf++) acc[uf][f] *= alpha;
        mrun[f] = mnew;
      }
      float psum = 0.f;
      unsigned short pk[16];
#pragma unroll
      for (int e = 0; e < 16; e++) {
        const float p = exp2f(z[e] - mnew);
        psum += p;
        pk[e] = f2bf(p);
      }
      psum += __shfl_xor(psum, 16);
      psum += __shfl_xor(psum, 32);
      lrun[f] += psum;
      // write P rows (i-local = f*16+li) into swizzled pbuf
#pragma unroll
      for (int jf = 0; jf < 4; jf++) {
        ushort4 w4;
        w4.x = pk[jf * 4 + 0];
        w4.y = pk[jf * 4 + 1];
        w4.z = pk[jf * 4 + 2];
        w4.w = pk[jf * 4 + 3];
        const int wb = (((f * 16 + li) * 64 + jf * 16 + lg * 4) * 2) ^ xr;
        *(ushort4*)(pbb + wb) = w4;
      }
    }

    // ---- PV: O^T[u][i] += V^T[u][j] P^T[j][i]  (same-wave LDS write->read, no barrier)
    s16x8 pfrag[2][2];
#pragma unroll
    for (int f = 0; f < 2; f++)
#pragma unroll
      for (int hh = 0; hh < 2; hh++) {
        const int rd = (((f * 16 + li) * 64 + hh * 32 + lg * 8) * 2) ^ xr;
        pfrag[f][hh] = *(const s16x8*)(pbb + rd);
      }
#pragma unroll
    for (int uf = 0; uf < 4; uf++) {
      const unsigned short* vr = Vtb + (size_t)(uf * 16 + li) * T_ + jb;
      s16x8 v0 = *(const s16x8*)(vr + lg * 8);
      s16x8 v1 = *(const s16x8*)(vr + 32 + lg * 8);
#pragma unroll
      for (int f = 0; f < 2; f++) {
        acc[uf][f] = mfma16(v0, pfrag[f][0], acc[uf][f]);
        acc[uf][f] = mfma16(v1, pfrag[f][1], acc[uf][f]);
      }
    }
  }

  // ---- epilogue: lane holds O^T[u = uf*16+lg*4+r][i = f*16+li]
#pragma unroll
  for (int f = 0; f < 2; f++) {
    const float inv = 1.0f / lrun[f];
    unsigned short* arow = att + ((size_t)(b * T_) + q0 + f * 16 + li) * 1024 + h * 64;
#pragma unroll
    for (int uf = 0; uf < 4; uf++) {
      ushort4 o;
      o.x = f2bf(acc[uf][f][0] * inv);
      o.y = f2bf(acc[uf][f][1] * inv);
      o.z = f2bf(acc[uf][f][2] * inv);
      o.w = f2bf(acc[uf][f][3] * inv);
      *(ushort4*)(arow + uf * 16 + lg * 4) = o;
    }
  }
}

// ----------------------------------------------------------------
extern "C" void kernel_launch(void* const* d_in, const int* in_sizes, int n_in,
                              void* d_out, int out_size, void* d_ws, size_t ws_size,
                              hipStream_t stream) {
  const float* x = (const float*)d_in[0];
  const int* mask = (const int*)d_in[1];
  const float* Wq = (const float*)d_in[2];
  const float* Wk = (const float*)d_in[3];
  const float* Wv = (const float*)d_in[4];
  const float* Wo = (const float*)d_in[5];

  const size_t MB = 1u << 20;
  char* ws = (char*)d_ws;
  unsigned short* wqT = (unsigned short*)(ws + 0 * MB);
  unsigned short* wkT = (unsigned short*)(ws + 2 * MB);
  unsigned short* wvT = (unsigned short*)(ws + 4 * MB);
  unsigned short* woT = (unsigned short*)(ws + 6 * MB);
  unsigned short* xb  = (unsigned short*)(ws + 8 * MB);   // 8MB; dead after QKV GEMM
  unsigned short* qb  = (unsigned short*)(ws + 16 * MB);  // 8MB
  unsigned short* kb  = (unsigned short*)(ws + 24 * MB);  // 8MB
  unsigned short* vb  = (unsigned short*)(ws + 32 * MB);  // 8MB; dead after vtrans
  unsigned short* vt  = xb;                               // reuse xb slot
  unsigned short* att = vb;                               // reuse vb slot
  (void)ws_size; (void)in_sizes; (void)n_in; (void)out_size;

  wtrans_kernel<<<dim3(16, 16, 4), 256, 0, stream>>>(Wq, Wk, Wv, Wo, wqT, wkT, wvT, woT);
  xmask_kernel<<<dim3(4096), 256, 0, stream>>>(x, mask, xb);
  gemm_qkv<<<dim3(8, 32, 3), 256, 0, stream>>>(xb, wqT, wkT, wvT, qb, kb, vb);
  vtrans_kernel<<<dim3(32, 32), 256, 0, stream>>>(vb, vt);
  attn2_kernel<<<dim3(32, 64), 64, 0, stream>>>(qb, kb, vt, mask, att);
  gemm_out<<<dim3(8, 32), 256, 0, stream>>>(att, woT, (float*)d_out);
}

// Round 4
// 161.273 us; speedup vs baseline: 2.0027x; 1.1276x over previous
//
#include <hip/hip_runtime.h>
#include <stdint.h>
#include <stddef.h>

#define B_ 2
#define T_ 2048
#define D_ 1024
#define H_ 16
#define U_ 64
#define M_ (B_ * T_)   // 4096
#define N_ (H_ * U_)   // 1024

typedef __attribute__((ext_vector_type(4))) float f32x4;
typedef __attribute__((ext_vector_type(8))) short s16x8;
typedef __attribute__((ext_vector_type(8))) __bf16 b16x8;

static_assert(sizeof(s16x8) == 16, "frag size");

__device__ __forceinline__ unsigned short f2bf(float f) {
  unsigned int u = __float_as_uint(f);
  u += 0x7FFFu + ((u >> 16) & 1u);     // RNE
  return (unsigned short)(u >> 16);
}

// --- MFMA wrapper: SFINAE hedge — works whether the builtin takes short8 or bf16x8
template <typename V>
__device__ __forceinline__ auto mfma16_impl(V a, V b, f32x4 c, int)
    -> decltype(__builtin_amdgcn_mfma_f32_16x16x32_bf16(a, b, c, 0, 0, 0)) {
  return __builtin_amdgcn_mfma_f32_16x16x32_bf16(a, b, c, 0, 0, 0);
}
template <typename V>
__device__ __forceinline__ f32x4 mfma16_impl(V a, V b, f32x4 c, long) {
  return __builtin_amdgcn_mfma_f32_16x16x32_bf16(
      __builtin_bit_cast(b16x8, a), __builtin_bit_cast(b16x8, b), c, 0, 0, 0);
}
__device__ __forceinline__ f32x4 mfma16(s16x8 a, s16x8 b, f32x4 c) {
  return mfma16_impl(a, b, c, 0);
}

// --- async global->LDS, 16B per lane (m97 lever)
__device__ __forceinline__ void gld16(const unsigned short* g, unsigned short* l) {
  __builtin_amdgcn_global_load_lds(
      (const __attribute__((address_space(1))) void*)g,
      (__attribute__((address_space(3))) void*)l, 16, 0, 0);
}

// ---------------------------------------------------------------- K0: W -> W^T (bf16)
__global__ void wtrans_kernel(const float* __restrict__ w0, const float* __restrict__ w1,
                              const float* __restrict__ w2, const float* __restrict__ w3,
                              unsigned short* __restrict__ o0, unsigned short* __restrict__ o1,
                              unsigned short* __restrict__ o2, unsigned short* __restrict__ o3) {
  __shared__ float tile[64][65];
  const float* w;
  unsigned short* o;
  switch (blockIdx.z) {
    case 0: w = w0; o = o0; break;
    case 1: w = w1; o = o1; break;
    case 2: w = w2; o = o2; break;
    default: w = w3; o = o3; break;
  }
  const int kb = blockIdx.y * 64, nb = blockIdx.x * 64;
  const int tid = threadIdx.x;
  const int r0 = tid >> 6, c = tid & 63;
#pragma unroll
  for (int i = 0; i < 16; i++) {
    int r = i * 4 + r0;
    tile[r][c] = w[(size_t)(kb + r) * 1024 + nb + c];
  }
  __syncthreads();
#pragma unroll
  for (int i = 0; i < 16; i++) {
    int r = i * 4 + r0;   // row of the transposed output (n index)
    o[(size_t)(nb + r) * 1024 + kb + c] = f2bf(tile[c][r]);
  }
}

// ---------------------------------------------------------------- K1: xb = bf16(x * mask)
__global__ void xmask_kernel(const float* __restrict__ x, const int* __restrict__ mask,
                             unsigned short* __restrict__ xb) {
  const int idx = (blockIdx.x * 256 + threadIdx.x) * 4;  // 4 elems/thread
  const int row = idx >> 10;                             // b*T + t
  const float m = (float)mask[row];
  float4 v = *(const float4*)(x + idx);
  ushort4 o;
  o.x = f2bf(v.x * m);
  o.y = f2bf(v.y * m);
  o.z = f2bf(v.z * m);
  o.w = f2bf(v.w * m);
  *(ushort4*)(xb + idx) = o;
}

// ---------------------------------------------------------------- GEMM (m97 structure):
// C[m][n] = sum_k A[m][k] * Bt[n][k]. 128x128 tile, BK=32, 4 waves, global_load_lds.
template <bool OUTF32>
__device__ __forceinline__ void gemm97_body(const unsigned short* __restrict__ A,
                                            const unsigned short* __restrict__ Bt,
                                            void* __restrict__ Cout) {
  constexpr int Kd = 1024, Nd = 1024;
  __shared__ unsigned short la[128 * 32];  // linear [row][32k], 64B/row
  __shared__ unsigned short lb[128 * 32];
  const int tid = threadIdx.x;
  const int lane = tid & 63;
  const int w = tid >> 6;
  const int mb = blockIdx.y * 128, nb = blockIdx.x * 128;
  const int wm = (w >> 1) * 64, wn = (w & 1) * 64;
  const int lr = lane & 15, lg = lane >> 4;
  // staging map: per-wave LDS base (lane0) + lane*16B == srow*32 + scol for all lanes
  const int srow = w * 16 + (lane >> 2);     // 0..63 (+64 for second issue)
  const int scol = (lane & 3) * 8;
  const unsigned short* gA = A + (size_t)(mb + srow) * Kd + scol;
  const unsigned short* gB = Bt + (size_t)(nb + srow) * Kd + scol;
  unsigned short* lA = la + srow * 32 + scol;
  unsigned short* lB = lb + srow * 32 + scol;

  f32x4 acc[4][4] = {};

  for (int kt = 0; kt < Kd; kt += 32) {
    gld16(gA + kt, lA);
    gld16(gA + kt + (size_t)64 * Kd, lA + 64 * 32);
    gld16(gB + kt, lB);
    gld16(gB + kt + (size_t)64 * Kd, lB + 64 * 32);
    __syncthreads();  // vmcnt(0)+barrier: staged data visible to all waves
    s16x8 af[4], bfr[4];
#pragma unroll
    for (int i = 0; i < 4; i++)
      af[i] = *(const s16x8*)(la + (wm + i * 16 + lr) * 32 + lg * 8);
#pragma unroll
    for (int j = 0; j < 4; j++)
      bfr[j] = *(const s16x8*)(lb + (wn + j * 16 + lr) * 32 + lg * 8);
#pragma unroll
    for (int i = 0; i < 4; i++)
#pragma unroll
      for (int j = 0; j < 4; j++)
        acc[i][j] = mfma16(af[i], bfr[j], acc[i][j]);
    __syncthreads();  // all waves done reading before next stage overwrites
  }

  // epilogue: lane holds C[row = wm+i*16+lg*4+r][col = wn+j*16+lr]
#pragma unroll
  for (int i = 0; i < 4; i++)
#pragma unroll
    for (int j = 0; j < 4; j++) {
      const int col = nb + wn + j * 16 + lr;
      const int rowb = mb + wm + i * 16 + lg * 4;
      if (OUTF32) {
        float* C = (float*)Cout;
#pragma unroll
        for (int r = 0; r < 4; r++) C[(size_t)(rowb + r) * Nd + col] = acc[i][j][r];
      } else {
        unsigned short* C = (unsigned short*)Cout;
#pragma unroll
        for (int r = 0; r < 4; r++) C[(size_t)(rowb + r) * Nd + col] = f2bf(acc[i][j][r]);
      }
    }
}

__global__ __launch_bounds__(256) void gemm_qkv(const unsigned short* __restrict__ A,
                                                const unsigned short* __restrict__ wq,
                                                const unsigned short* __restrict__ wk,
                                                const unsigned short* __restrict__ wv,
                                                unsigned short* __restrict__ cq,
                                                unsigned short* __restrict__ ck,
                                                unsigned short* __restrict__ cv) {
  const unsigned short* Bt;
  unsigned short* C;
  if (blockIdx.z == 0) { Bt = wq; C = cq; }
  else if (blockIdx.z == 1) { Bt = wk; C = ck; }
  else { Bt = wv; C = cv; }
  gemm97_body<false>(A, Bt, C);
}

__global__ __launch_bounds__(256) void gemm_out(const unsigned short* __restrict__ A,
                                                const unsigned short* __restrict__ woT,
                                                float* __restrict__ C) {
  gemm97_body<true>(A, woT, C);
}

// ---------------------------------------------------------------- K2.5: V -> V^T per (b,h)
__global__ void vtrans_kernel(const unsigned short* __restrict__ vb,
                              unsigned short* __restrict__ vt) {
  __shared__ unsigned short tile[64][65];
  const int bh = blockIdx.y;           // 0..31
  const int tb = blockIdx.x * 64;      // t base
  const int tid = threadIdx.x;
  const int r0 = tid >> 6, c = tid & 63;
  const unsigned short* src = vb + ((size_t)(bh >> 4) * T_ + tb) * 1024 + (bh & 15) * 64;
#pragma unroll
  for (int i = 0; i < 16; i++) {
    int r = i * 4 + r0;
    tile[r][c] = src[(size_t)r * 1024 + c];
  }
  __syncthreads();
  unsigned short* dst = vt + (size_t)bh * 64 * T_ + tb;
#pragma unroll
  for (int i = 0; i < 16; i++) {
    int u = i * 4 + r0;
    dst[(size_t)u * T_ + c] = tile[c][u];
  }
}

// ---------------------------------------------------------------- K3: flash attention v5
// One wave per 32 q-rows of one (b,h). KVBLK=64. attn2-proven inner structure;
// V loads hoisted between QK^T and softmax (fly under the VALU work).
__global__ __launch_bounds__(64, 2) void attn5_kernel(const unsigned short* __restrict__ Q,
                                                      const unsigned short* __restrict__ K,
                                                      const unsigned short* __restrict__ Vt,
                                                      const int* __restrict__ mask,
                                                      unsigned short* __restrict__ att) {
  __shared__ unsigned short pbuf[32 * 64];  // P repack, XOR-swizzled, 4KB
  const int lane = threadIdx.x & 63;
  const int li = lane & 15, lg = lane >> 4;
  const int bh = blockIdx.x;
  const int b = bh >> 4, h = bh & 15;
  const int qg = 63 - blockIdx.y;          // longest-first dispatch
  const int q0 = qg * 32;

  const float CS = 0.125f * 1.44269504089f;   // 1/sqrt(U) * log2(e)
  const float PB = 10000.0f * 1.44269504089f; // pad bias, log2 domain

  s16x8 qf[2][2];
#pragma unroll
  for (int f = 0; f < 2; f++) {
    const unsigned short* qrow = Q + ((size_t)(b * T_) + q0 + f * 16 + li) * 1024 + h * 64;
    qf[f][0] = *(const s16x8*)(qrow + lg * 8);
    qf[f][1] = *(const s16x8*)(qrow + 32 + lg * 8);
  }

  const unsigned short* Kb = K + (size_t)(b * T_) * 1024 + h * 64;
  const unsigned short* Vtb = Vt + (size_t)bh * 64 * T_;
  const int* mk = mask + b * T_;

  const int iq0 = q0 + li, iq1 = q0 + 16 + li;

  float mrun[2] = {-1e30f, -1e30f}, lrun[2] = {0.f, 0.f};
  f32x4 acc[4][2] = {};  // [ufrag][ifrag]

  const int xr = (li & 3) << 5;
  char* pbb = (char*)pbuf;

  const int ntiles = (q0 + 95) >> 6;  // ceil((q0+32)/64)
  for (int t = 0; t < ntiles; t++) {
    const int jb = t * 64;
    const bool diag = (jb + 64 > q0);  // wave-uniform

    // ---- K fragments + QK^T (swapped): s[jf][f], lane holds j=jb+jf*16+lg*4+r, i=q0+f*16+li
    f32x4 s[4][2] = {};
#pragma unroll
    for (int jf = 0; jf < 4; jf++) {
      const unsigned short* kr = Kb + (size_t)(jb + jf * 16 + li) * 1024 + lg * 8;
      s16x8 ka = *(const s16x8*)kr;
      s16x8 kc = *(const s16x8*)(kr + 32);
      s[jf][0] = mfma16(ka, qf[0][0], s[jf][0]);
      s[jf][0] = mfma16(kc, qf[0][1], s[jf][0]);
      s[jf][1] = mfma16(ka, qf[1][0], s[jf][1]);
      s[jf][1] = mfma16(kc, qf[1][1], s[jf][1]);
    }

    // ---- V fragments for this tile (independent loads; fly under softmax)
    s16x8 vf[4][2];
#pragma unroll
    for (int uf = 0; uf < 4; uf++) {
      const unsigned short* vr = Vtb + (size_t)(uf * 16 + li) * T_ + jb + lg * 8;
      vf[uf][0] = *(const s16x8*)vr;
      vf[uf][1] = *(const s16x8*)(vr + 32);
    }

    // ---- key padding bias, hoisted per tile (shared across ifrags)
    float bias[4][4];
#pragma unroll
    for (int jf = 0; jf < 4; jf++) {
      int4 mv = *(const int4*)(mk + jb + jf * 16 + lg * 4);
      bias[jf][0] = mv.x ? 0.f : -PB;
      bias[jf][1] = mv.y ? 0.f : -PB;
      bias[jf][2] = mv.z ? 0.f : -PB;
      bias[jf][3] = mv.w ? 0.f : -PB;
    }

    // ---- online softmax per ifrag (log2 domain)
#pragma unroll
    for (int f = 0; f < 2; f++) {
      const int iq = f ? iq1 : iq0;
      float pmax = -1e30f;
#pragma unroll
      for (int jf = 0; jf < 4; jf++) {
        f32x4 zz;
#pragma unroll
        for (int r = 0; r < 4; r++) {
          float z = fmaf(s[jf][f][r], CS, bias[jf][r]);
          if (diag && (jb + jf * 16 + lg * 4 + r > iq)) z = -1e30f;
          zz[r] = z;
          pmax = fmaxf(pmax, z);
        }
        s[jf][f] = zz;
      }
      pmax = fmaxf(pmax, __shfl_xor(pmax, 16));
      pmax = fmaxf(pmax, __shfl_xor(pmax, 32));
      if (!__all(pmax <= mrun[f])) {  // exact-skip rescale (alpha==1 when skipped)
        const float mnew = fmaxf(mrun[f], pmax);
        const float al = exp2f(mrun[f] - mnew);
        lrun[f] *= al;
#pragma unroll
        for (int uf = 0; uf < 4; uf++) acc[uf][f] *= al;
        mrun[f] = mnew;
      }
      const float mm = mrun[f];
      float psum = 0.f;
#pragma unroll
      for (int jf = 0; jf < 4; jf++) {
        ushort4 w4;
#pragma unroll
        for (int r = 0; r < 4; r++) {
          const float p = exp2f(s[jf][f][r] - mm);
          psum += p;
          ((unsigned short*)&w4)[r] = __builtin_bit_cast(unsigned short, (__bf16)p);
        }
        const int wb = (((f * 16 + li) * 64 + jf * 16 + lg * 4) * 2) ^ xr;
        *(ushort4*)(pbb + wb) = w4;
      }
      psum += __shfl_xor(psum, 16);
      psum += __shfl_xor(psum, 32);
      lrun[f] += psum;
    }

    // ---- PV (same-wave LDS write->read; single wave per block)
    s16x8 pfrag[2][2];
#pragma unroll
    for (int f = 0; f < 2; f++)
#pragma unroll
      for (int hh = 0; hh < 2; hh++) {
        const int rd = (((f * 16 + li) * 64 + hh * 32 + lg * 8) * 2) ^ xr;
        pfrag[f][hh] = *(const s16x8*)(pbb + rd);
      }
#pragma unroll
    for (int uf = 0; uf < 4; uf++)
#pragma unroll
      for (int f = 0; f < 2; f++) {
        acc[uf][f] = mfma16(vf[uf][0], pfrag[f][0], acc[uf][f]);
        acc[uf][f] = mfma16(vf[uf][1], pfrag[f][1], acc[uf][f]);
      }
  }

  // ---- epilogue: lane holds O^T[u = uf*16+lg*4+r][i = f*16+li]
#pragma unroll
  for (int f = 0; f < 2; f++) {
    const float inv = 1.0f / lrun[f];
    unsigned short* arow = att + ((size_t)(b * T_) + q0 + f * 16 + li) * 1024 + h * 64;
#pragma unroll
    for (int uf = 0; uf < 4; uf++) {
      ushort4 o;
#pragma unroll
      for (int r = 0; r < 4; r++)
        ((unsigned short*)&o)[r] = __builtin_bit_cast(unsigned short, (__bf16)(acc[uf][f][r] * inv));
      *(ushort4*)(arow + uf * 16 + lg * 4) = o;
    }
  }
}

// ----------------------------------------------------------------
extern "C" void kernel_launch(void* const* d_in, const int* in_sizes, int n_in,
                              void* d_out, int out_size, void* d_ws, size_t ws_size,
                              hipStream_t stream) {
  const float* x = (const float*)d_in[0];
  const int* mask = (const int*)d_in[1];
  const float* Wq = (const float*)d_in[2];
  const float* Wk = (const float*)d_in[3];
  const float* Wv = (const float*)d_in[4];
  const float* Wo = (const float*)d_in[5];

  const size_t MB = 1u << 20;
  char* ws = (char*)d_ws;
  unsigned short* wqT = (unsigned short*)(ws + 0 * MB);
  unsigned short* wkT = (unsigned short*)(ws + 2 * MB);
  unsigned short* wvT = (unsigned short*)(ws + 4 * MB);
  unsigned short* woT = (unsigned short*)(ws + 6 * MB);
  unsigned short* xb  = (unsigned short*)(ws + 8 * MB);   // 8MB; dead after QKV GEMM
  unsigned short* qb  = (unsigned short*)(ws + 16 * MB);  // 8MB
  unsigned short* kb  = (unsigned short*)(ws + 24 * MB);  // 8MB
  unsigned short* vb  = (unsigned short*)(ws + 32 * MB);  // 8MB; dead after vtrans
  unsigned short* vt  = xb;                               // reuse xb slot
  unsigned short* att = vb;                               // reuse vb slot
  (void)ws_size; (void)in_sizes; (void)n_in; (void)out_size;

  wtrans_kernel<<<dim3(16, 16, 4), 256, 0, stream>>>(Wq, Wk, Wv, Wo, wqT, wkT, wvT, woT);
  xmask_kernel<<<dim3(4096), 256, 0, stream>>>(x, mask, xb);
  gemm_qkv<<<dim3(8, 32, 3), 256, 0, stream>>>(xb, wqT, wkT, wvT, qb, kb, vb);
  vtrans_kernel<<<dim3(32, 32), 256, 0, stream>>>(vb, vt);
  attn5_kernel<<<dim3(32, 64), 64, 0, stream>>>(qb, kb, vt, mask, att);
  gemm_out<<<dim3(8, 32), 256, 0, stream>>>(att, woT, (float*)d_out);
}